// Round 1
// baseline (246.870 us; speedup 1.0000x reference)
//
#include <hip/hip_runtime.h>

typedef __bf16 bf16x8 __attribute__((ext_vector_type(8)));
typedef float f32x4 __attribute__((ext_vector_type(4)));

__device__ __forceinline__ unsigned short f2bf(float x) {
  union { float f; unsigned u; } a; a.f = x;
  unsigned r = a.u + 0x7FFFu + ((a.u >> 16) & 1u);
  return (unsigned short)(r >> 16);
}

// ---------------------------------------------------------------------------
// Pre-pass: transpose v (fp32, [pos][kv][d]) -> Vt bf16 [kv][d][pos]
// grid (32 sblk, 8 kv), block 256
// ---------------------------------------------------------------------------
__global__ __launch_bounds__(256) void vtrans_kernel(const float* __restrict__ v,
                                                     unsigned short* __restrict__ Vt) {
  const int sblk = blockIdx.x, kv = blockIdx.y;
  __shared__ float T[64 * 128];  // [pos][d]
  const int t = threadIdx.x;
  for (int j = 0; j < 8; ++j) {
    int f4 = j * 256 + t;          // 0..2047
    int pos = f4 >> 5;
    int doff = (f4 & 31) * 4;
    float4 src = *(const float4*)&v[(((size_t)(sblk * 64 + pos)) * 8 + kv) * 128 + doff];
    *(float4*)&T[pos * 128 + doff] = src;
  }
  __syncthreads();
  const int d = t >> 1, ph = t & 1;
  unsigned short tmp[32];
#pragma unroll
  for (int i = 0; i < 32; ++i) tmp[i] = f2bf(T[(ph * 32 + i) * 128 + d]);
  size_t base = ((size_t)kv * 128 + d) * 2048 + sblk * 64 + ph * 32;
#pragma unroll
  for (int c = 0; c < 4; ++c) {
    uint4 u;
    u.x = (unsigned)tmp[c * 8 + 0] | ((unsigned)tmp[c * 8 + 1] << 16);
    u.y = (unsigned)tmp[c * 8 + 2] | ((unsigned)tmp[c * 8 + 3] << 16);
    u.z = (unsigned)tmp[c * 8 + 4] | ((unsigned)tmp[c * 8 + 5] << 16);
    u.w = (unsigned)tmp[c * 8 + 6] | ((unsigned)tmp[c * 8 + 7] << 16);
    *(uint4*)&Vt[base + c * 8] = u;
  }
}

// ---------------------------------------------------------------------------
// Selection: one wave per (kv, m). Emits uint32 bitmask of selected blocks.
// grid 4096 blocks x 256 (4 waves/block)
// ---------------------------------------------------------------------------
__global__ __launch_bounds__(256) void sel_kernel(const float* __restrict__ p,
                                                  unsigned* __restrict__ sm) {
  const int wid = blockIdx.x * 4 + (threadIdx.x >> 6);
  const int lane = threadIdx.x & 63;
  const int kv = wid >> 11;
  const int m = wid & 2047;
  const int rb = m >> 6;
  const int s = lane & 31;
  const int c0 = 4 * s - 1;
  float best = -1.f;
  for (int g = 0; g < 2; ++g) {
    int h = kv * 4 + (lane >> 5) * 2 + g;
    const float* pr = p + ((size_t)h * 2048 + m) * 127;
    float acc = 0.f;
    if (c0 >= 0) acc = fmaf(pr[c0], 1.f, acc);        // ascending-c FMA chain
    acc = fmaf(pr[c0 + 1], 2.f, acc);                 // mirrors BLAS K-loop
    acc = fmaf(pr[c0 + 2], 2.f, acc);
    acc = fmaf(pr[c0 + 3], 2.f, acc);
    if (c0 + 4 < 127) acc = fmaf(pr[c0 + 4], 1.f, acc);
    best = fmaxf(best, acc);
  }
  best = fmaxf(best, __shfl_xor(best, 32));           // max over 4 heads in group
  const int rbm1 = rb > 0 ? rb - 1 : 0;
  if (s == 0 || s == rb || s == rbm1) best = 999999.0f;  // KEEP
  const int kmax = min(rb + 1, 16);
  unsigned msk = 0;
  float val = best;
  for (int it = 0; it < kmax; ++it) {
    float v = val; int idx = s;
#pragma unroll
    for (int off = 1; off < 32; off <<= 1) {          // argmax, lower-index ties
      float ov = __shfl_xor(v, off);
      int oi = __shfl_xor(idx, off);
      if (ov > v || (ov == v && oi < idx)) { v = ov; idx = oi; }
    }
    msk |= (1u << idx);
    if (s == idx) val = -2.f;
  }
  if (lane == 0) sm[(size_t)kv * 2048 + m] = msk;
}

// ---------------------------------------------------------------------------
// Attention: WG = (64-row q-tile, one q-head). 4 waves x 16 rows.
// grid (32 qtile, 32 head), block 256
// ---------------------------------------------------------------------------
__global__ __launch_bounds__(256) void attn_kernel(const float* __restrict__ q,
                                                   const float* __restrict__ k,
                                                   const unsigned short* __restrict__ Vt,
                                                   const unsigned* __restrict__ sm,
                                                   float* __restrict__ out) {
  const int m0 = blockIdx.x * 64;
  const int rb = blockIdx.x;
  const int h = blockIdx.y;
  const int kv = h >> 2;
  const int tid = threadIdx.x;
  const int w = tid >> 6, lane = tid & 63;
  const int cl = lane & 15, hi = lane >> 4;
  const int wbase = w * 16;

  __shared__ unsigned short Klds[64 * 128];   // [key][kdim], chunk ^= (key&7)
  __shared__ unsigned short Vlds[128 * 64];   // [d][key],    chunk ^= (d&7)
  __shared__ unsigned short Plds[4][16 * 64]; // per-wave, chunk ^= (row&7)
  __shared__ unsigned Ush;

  // Q fragments: A-layout, row = cl, k = kst*32 + hi*8 + i
  bf16x8 qf[4];
  {
    const float* qp = q + ((size_t)(m0 + wbase + cl) * 32 + h) * 128 + hi * 8;
#pragma unroll
    for (int kst = 0; kst < 4; ++kst) {
      float4 a = *(const float4*)(qp + kst * 32);
      float4 b = *(const float4*)(qp + kst * 32 + 4);
      union { bf16x8 v; unsigned short u[8]; } tmp;
      tmp.u[0] = f2bf(a.x); tmp.u[1] = f2bf(a.y); tmp.u[2] = f2bf(a.z); tmp.u[3] = f2bf(a.w);
      tmp.u[4] = f2bf(b.x); tmp.u[5] = f2bf(b.y); tmp.u[6] = f2bf(b.z); tmp.u[7] = f2bf(b.w);
      qf[kst] = tmp.v;
    }
  }
  unsigned selr[4]; int rowg[4];
#pragma unroll
  for (int r = 0; r < 4; ++r) {
    rowg[r] = m0 + wbase + hi * 4 + r;
    selr[r] = sm[(size_t)kv * 2048 + rowg[r]];
  }
  if (tid == 0) Ush = 0;
  __syncthreads();
  if (tid < 64) atomicOr(&Ush, sm[(size_t)kv * 2048 + m0 + tid]);
  __syncthreads();
  unsigned U = Ush;
  if (rb < 31) U &= (1u << (rb + 1)) - 1u;  // drop non-causal picks

  f32x4 oacc[8];
#pragma unroll
  for (int ct = 0; ct < 8; ++ct) oacc[ct] = f32x4{0.f, 0.f, 0.f, 0.f};
  float mrun[4] = {-INFINITY, -INFINITY, -INFINITY, -INFINITY};
  float lrun[4] = {0.f, 0.f, 0.f, 0.f};
  const float scale = 0.08838834764831845f;

  for (int s = 0; s <= rb; ++s) {
    if (!((U >> s) & 1u)) continue;
    __syncthreads();
    // --- stage K (fp32 -> bf16), 64 keys x 128 d
#pragma unroll
    for (int j = 0; j < 4; ++j) {
      int cid = j * 256 + tid;
      int row = cid >> 4, c = cid & 15;
      const float* kp = k + (((size_t)(s * 64 + row) * 8) + kv) * 128 + c * 8;
      float4 a = *(const float4*)kp;
      float4 b = *(const float4*)(kp + 4);
      union { bf16x8 v; unsigned short u[8]; } tmp;
      tmp.u[0] = f2bf(a.x); tmp.u[1] = f2bf(a.y); tmp.u[2] = f2bf(a.z); tmp.u[3] = f2bf(a.w);
      tmp.u[4] = f2bf(b.x); tmp.u[5] = f2bf(b.y); tmp.u[6] = f2bf(b.z); tmp.u[7] = f2bf(b.w);
      *(bf16x8*)&Klds[row * 128 + ((c ^ (row & 7)) * 8)] = tmp.v;
    }
    // --- stage V^T (bf16 direct copy), 128 d x 64 keys
#pragma unroll
    for (int j = 0; j < 4; ++j) {
      int cid = j * 256 + tid;
      int d = cid >> 3, c = cid & 7;
      uint4 src = *(const uint4*)&Vt[((size_t)kv * 128 + d) * 2048 + s * 64 + c * 8];
      *(uint4*)&Vlds[d * 64 + ((c ^ (d & 7)) * 8)] = src;
    }
    __syncthreads();

    // --- QK^T: 16 rows x 64 keys per wave
    f32x4 sf[4];
#pragma unroll
    for (int jt = 0; jt < 4; ++jt) {
      f32x4 acc = f32x4{0.f, 0.f, 0.f, 0.f};
#pragma unroll
      for (int kst = 0; kst < 4; ++kst) {
        bf16x8 kb = *(const bf16x8*)&Klds[(jt * 16 + cl) * 128 + (((kst * 4 + hi) ^ (cl & 7)) * 8)];
        acc = __builtin_amdgcn_mfma_f32_16x16x32_bf16(qf[kst], kb, acc, 0, 0, 0);
      }
      sf[jt] = acc;
    }
    // --- mask + scale
#pragma unroll
    for (int jt = 0; jt < 4; ++jt) {
#pragma unroll
      for (int r = 0; r < 4; ++r) {
        float x = sf[jt][r] * scale;
        bool ok = (selr[r] >> s) & 1u;
        if (s == rb) ok = ok && (s * 64 + jt * 16 + cl) <= rowg[r];
        sf[jt][r] = ok ? x : -INFINITY;
      }
    }
    // --- online softmax per row (rows hi*4+r, cols across 16-lane group)
#pragma unroll
    for (int r = 0; r < 4; ++r) {
      float mx = fmaxf(fmaxf(sf[0][r], sf[1][r]), fmaxf(sf[2][r], sf[3][r]));
#pragma unroll
      for (int off = 1; off < 16; off <<= 1) mx = fmaxf(mx, __shfl_xor(mx, off));
      float mn = fmaxf(mrun[r], mx);
      float sum = 0.f;
#pragma unroll
      for (int jt = 0; jt < 4; ++jt) {
        float e = __expf(sf[jt][r] - mn);
        sf[jt][r] = e;
        sum += e;
      }
#pragma unroll
      for (int off = 1; off < 16; off <<= 1) sum += __shfl_xor(sum, off);
      float alpha = __expf(mrun[r] - mn);
      lrun[r] = lrun[r] * alpha + sum;
      mrun[r] = mn;
#pragma unroll
      for (int ct = 0; ct < 8; ++ct) oacc[ct][r] *= alpha;
    }
    // --- P -> LDS (bf16, A-frag layout for PV)
    unsigned short* pl = &Plds[w][0];
#pragma unroll
    for (int jt = 0; jt < 4; ++jt) {
#pragma unroll
      for (int r = 0; r < 4; ++r) {
        int row = hi * 4 + r;
        int col = jt * 16 + cl;
        pl[row * 64 + (((col >> 3) ^ (row & 7)) * 8) + (col & 7)] = f2bf(sf[jt][r]);
      }
    }
    // --- PV: O += P(16x64) * V(64x128)
#pragma unroll
    for (int kst = 0; kst < 2; ++kst) {
      bf16x8 pf = *(const bf16x8*)&pl[cl * 64 + (((kst * 4 + hi) ^ (cl & 7)) * 8)];
#pragma unroll
      for (int ct = 0; ct < 8; ++ct) {
        bf16x8 vb = *(const bf16x8*)&Vlds[(ct * 16 + cl) * 64 + (((kst * 4 + hi) ^ (cl & 7)) * 8)];
        oacc[ct] = __builtin_amdgcn_mfma_f32_16x16x32_bf16(pf, vb, oacc[ct], 0, 0, 0);
      }
    }
  }
  // --- epilogue: O / l, write (b, m, h, d) fp32
#pragma unroll
  for (int r = 0; r < 4; ++r) {
    float inv = 1.f / lrun[r];
    float* op = out + ((size_t)rowg[r] * 32 + h) * 128 + cl;
#pragma unroll
    for (int ct = 0; ct < 8; ++ct) op[ct * 16] = oacc[ct][r] * inv;
  }
}

extern "C" void kernel_launch(void* const* d_in, const int* in_sizes, int n_in,
                              void* d_out, int out_size, void* d_ws, size_t ws_size,
                              hipStream_t stream) {
  const float* q = (const float*)d_in[0];
  const float* k = (const float*)d_in[1];
  const float* v = (const float*)d_in[2];
  const float* p = (const float*)d_in[3];
  float* out = (float*)d_out;
  // ws layout: [0, 4MB) Vt bf16 [kv][d][pos]; [4MB, +64KB) selmask uint32
  unsigned short* Vt = (unsigned short*)d_ws;
  unsigned* sm = (unsigned*)((char*)d_ws + (size_t)8 * 128 * 2048 * 2);

  vtrans_kernel<<<dim3(32, 8), 256, 0, stream>>>(v, Vt);
  sel_kernel<<<4096, 256, 0, stream>>>(p, sm);
  attn_kernel<<<dim3(32, 32), 256, 0, stream>>>(q, k, Vt, sm, out);
}

// Round 3
// 151.099 us; speedup vs baseline: 1.6338x; 1.6338x over previous
//
#include <hip/hip_runtime.h>

typedef __bf16 bf16x8 __attribute__((ext_vector_type(8)));
typedef float f32x4 __attribute__((ext_vector_type(4)));

__device__ __forceinline__ unsigned short f2bf(float x) {
  union { float f; unsigned u; } a; a.f = x;
  unsigned r = a.u + 0x7FFFu + ((a.u >> 16) & 1u);
  return (unsigned short)(r >> 16);
}

__device__ __forceinline__ float exp2f_fast(float x) {
  return __builtin_amdgcn_exp2f(x);  // v_exp_f32: 2^x
}

__device__ __forceinline__ void gl_lds16(const void* g, void* l) {
  __builtin_amdgcn_global_load_lds(
      (const __attribute__((address_space(1))) void*)g,
      (__attribute__((address_space(3))) void*)l, 16, 0, 0);
}

// ---------------------------------------------------------------------------
// k (fp32 [pos][kv][d]) -> Kb bf16 [kv][pos][d]
// ---------------------------------------------------------------------------
__global__ __launch_bounds__(256) void kconv_kernel(const float* __restrict__ k,
                                                    unsigned short* __restrict__ Kb) {
  int t = blockIdx.x * 256 + threadIdx.x;  // 262144 threads, 8 elems each
  int o = t * 8;
  int kv = o >> 18;
  int pos = (o >> 7) & 2047;
  int d = o & 127;
  const float* src = k + ((size_t)pos * 8 + kv) * 128 + d;
  float4 a = *(const float4*)src;
  float4 b = *(const float4*)(src + 4);
  union { bf16x8 v; unsigned short u[8]; } w;
  w.u[0] = f2bf(a.x); w.u[1] = f2bf(a.y); w.u[2] = f2bf(a.z); w.u[3] = f2bf(a.w);
  w.u[4] = f2bf(b.x); w.u[5] = f2bf(b.y); w.u[6] = f2bf(b.z); w.u[7] = f2bf(b.w);
  *(bf16x8*)&Kb[o] = w.v;
}

// ---------------------------------------------------------------------------
// v (fp32 [pos][kv][d]) -> Vt bf16 [kv][d][pos]
// ---------------------------------------------------------------------------
__global__ __launch_bounds__(256) void vtrans_kernel(const float* __restrict__ v,
                                                     unsigned short* __restrict__ Vt) {
  const int sblk = blockIdx.x, kv = blockIdx.y;
  __shared__ float T[64 * 128];
  const int t = threadIdx.x;
  for (int j = 0; j < 8; ++j) {
    int f4 = j * 256 + t;
    int pos = f4 >> 5;
    int doff = (f4 & 31) * 4;
    float4 src = *(const float4*)&v[(((size_t)(sblk * 64 + pos)) * 8 + kv) * 128 + doff];
    *(float4*)&T[pos * 128 + doff] = src;
  }
  __syncthreads();
  const int d = t >> 1, ph = t & 1;
  unsigned short tmp[32];
#pragma unroll
  for (int i = 0; i < 32; ++i) tmp[i] = f2bf(T[(ph * 32 + i) * 128 + d]);
  size_t base = ((size_t)kv * 128 + d) * 2048 + sblk * 64 + ph * 32;
#pragma unroll
  for (int c = 0; c < 4; ++c) {
    uint4 u;
    u.x = (unsigned)tmp[c * 8 + 0] | ((unsigned)tmp[c * 8 + 1] << 16);
    u.y = (unsigned)tmp[c * 8 + 2] | ((unsigned)tmp[c * 8 + 3] << 16);
    u.z = (unsigned)tmp[c * 8 + 4] | ((unsigned)tmp[c * 8 + 5] << 16);
    u.w = (unsigned)tmp[c * 8 + 6] | ((unsigned)tmp[c * 8 + 7] << 16);
    *(uint4*)&Vt[base + c * 8] = u;
  }
}

// ---------------------------------------------------------------------------
// Selection: one wave per (kv, m). Emits uint32 bitmask of selected blocks.
// ---------------------------------------------------------------------------
__global__ __launch_bounds__(256) void sel_kernel(const float* __restrict__ p,
                                                  unsigned* __restrict__ sm) {
  const int wid = blockIdx.x * 4 + (threadIdx.x >> 6);
  const int lane = threadIdx.x & 63;
  const int kv = wid >> 11;
  const int m = wid & 2047;
  const int rb = m >> 6;
  const int s = lane & 31;
  const int c0 = 4 * s - 1;
  float best = -1.f;
  for (int g = 0; g < 2; ++g) {
    int h = kv * 4 + (lane >> 5) * 2 + g;
    const float* pr = p + ((size_t)h * 2048 + m) * 127;
    float acc = 0.f;
    if (c0 >= 0) acc = fmaf(pr[c0], 1.f, acc);
    acc = fmaf(pr[c0 + 1], 2.f, acc);
    acc = fmaf(pr[c0 + 2], 2.f, acc);
    acc = fmaf(pr[c0 + 3], 2.f, acc);
    if (c0 + 4 < 127) acc = fmaf(pr[c0 + 4], 1.f, acc);
    best = fmaxf(best, acc);
  }
  best = fmaxf(best, __shfl_xor(best, 32));
  const int rbm1 = rb > 0 ? rb - 1 : 0;
  if (s == 0 || s == rb || s == rbm1) best = 999999.0f;
  const int kmax = min(rb + 1, 16);
  unsigned msk = 0;
  float val = best;
  for (int it = 0; it < kmax; ++it) {
    float v = val; int idx = s;
#pragma unroll
    for (int off = 1; off < 32; off <<= 1) {
      float ov = __shfl_xor(v, off);
      int oi = __shfl_xor(idx, off);
      if (ov > v || (ov == v && oi < idx)) { v = ov; idx = oi; }
    }
    msk |= (1u << idx);
    if (s == idx) val = -2.f;
  }
  if (lane == 0) sm[(size_t)kv * 2048 + m] = msk;
}

// ---------------------------------------------------------------------------
// Attention: WG = 128 rows (2 rb-tiles) x 1 head, 8 waves x 16 rows.
// Swapped QK^T (mfma(K,Q)); keymap makes P land in PV B-frag layout for free.
// Double-buffered LDS staging via global_load_lds + counted vmcnt.
// grid (128, 4): blockIdx.x = z*8 + kv (z descending), blockIdx.y = head-in-group
// ---------------------------------------------------------------------------
__global__ __launch_bounds__(512, 4) void attn_kernel(
    const unsigned short* __restrict__ Kb,
    const unsigned short* __restrict__ Vt,
    const float* __restrict__ q,
    const unsigned* __restrict__ sm,
    float* __restrict__ out) {
  const int kv = blockIdx.x & 7;
  const int z = 15 - (blockIdx.x >> 3);     // big tiles dispatched first (LPT)
  const int h = kv * 4 + blockIdx.y;
  const int m0 = z * 128;
  const int tid = threadIdx.x;
  const int w = tid >> 6, lane = tid & 63;
  const int cl = lane & 15, hi = lane >> 4;
  const int rowg = m0 + w * 16 + cl;        // this lane's q-row
  const int myrb = (m0 + w * 16) >> 6;      // wave-uniform
  const int rbU = 2 * z + 1;

  __shared__ unsigned short Klds[2][64 * 128];  // [key][d], chunk16 ^ x(key)
  __shared__ unsigned short Vlds[2][128 * 64];  // [d][pos], chunk8 ^ (d&7)
  __shared__ unsigned Ush;

  // Q B-frags (scale * log2e folded in)
  const float qs = 0.08838834764831845f * 1.4426950408889634f;
  bf16x8 qf[4];
  {
    const float* qp = q + ((size_t)rowg * 32 + h) * 128 + hi * 8;
#pragma unroll
    for (int kst = 0; kst < 4; ++kst) {
      float4 a = *(const float4*)(qp + kst * 32);
      float4 b = *(const float4*)(qp + kst * 32 + 4);
      union { bf16x8 v; unsigned short u[8]; } t;
      t.u[0] = f2bf(a.x * qs); t.u[1] = f2bf(a.y * qs); t.u[2] = f2bf(a.z * qs); t.u[3] = f2bf(a.w * qs);
      t.u[4] = f2bf(b.x * qs); t.u[5] = f2bf(b.y * qs); t.u[6] = f2bf(b.z * qs); t.u[7] = f2bf(b.w * qs);
      qf[kst] = t.v;
    }
  }
  unsigned selmask = sm[(size_t)kv * 2048 + rowg];
  unsigned uW = selmask;
#pragma unroll
  for (int off = 1; off < 16; off <<= 1) uW |= __shfl_xor(uW, off);
  if (tid == 0) Ush = 0;
  __syncthreads();
  if (lane == 0) atomicOr(&Ush, uW);
  __syncthreads();
  const unsigned U = Ush & ((2u << rbU) - 1u);
  const unsigned aW = uW & ((2u << myrb) - 1u);

  // stage one 64-key block into buffer b: 4 global_load_lds x 16B per wave
  auto STAGE = [&](int b, int s) {
#pragma unroll
    for (int pass = 0; pass < 2; ++pass) {
      int cid = pass * 512 + w * 64 + lane;
      int key = cid >> 4, c = cid & 15;
      int xk = (key & 3) | ((key >> 1) & 12);
      gl_lds16(Kb + (size_t)(kv * 2048 + s * 64 + key) * 128 + ((c ^ xk) * 8),
               &Klds[b][(pass * 512 + w * 64) * 8]);
    }
#pragma unroll
    for (int pass = 0; pass < 2; ++pass) {
      int cid = pass * 512 + w * 64 + lane;
      int d = cid >> 3, c = cid & 7;
      gl_lds16(Vt + (size_t)(kv * 128 + d) * 2048 + s * 64 + ((c ^ (d & 7)) * 8),
               &Vlds[b][(pass * 512 + w * 64) * 8]);
    }
  };

  f32x4 oacc[8];
#pragma unroll
  for (int i = 0; i < 8; ++i) oacc[i] = f32x4{0.f, 0.f, 0.f, 0.f};
  float mrun = -3.0e38f, lrun = 0.f;

  int s = 0;  // bit 0 of U is always set (block 0 is KEEP for every row)
  int cur = 0;
  STAGE(0, 0);
  while (s >= 0) {
    int ns = -1;
    if (s < 31) {
      unsigned rest = U >> (s + 1);
      if (rest) ns = s + 1 + __builtin_ctz(rest);
    }
    if (ns >= 0) {
      STAGE(cur ^ 1, ns);
      asm volatile("s_waitcnt vmcnt(4)" ::: "memory");  // cur staged; next in flight
    } else {
      asm volatile("s_waitcnt vmcnt(0)" ::: "memory");
    }
    __builtin_amdgcn_s_barrier();
    asm volatile("" ::: "memory");
    if ((s <= myrb) && ((aW >> s) & 1u)) {
      const unsigned short* KL = &Klds[cur][0];
      const unsigned short* VL = &Vlds[cur][0];
      // --- QK^T (swapped: A=K, B=Q). keymap: key(jt,i)=(jt&1)*32+(jt>>1)*4+8*(i>>2)+(i&3)
      float pv[16];
      const bool rowsel = (selmask >> s) & 1u;
      const bool edge = (s == myrb);
#pragma unroll
      for (int jt = 0; jt < 4; ++jt) {
        int keyb = (jt & 1) * 32 + ((jt >> 1) << 2) + ((cl >> 2) << 3) + (cl & 3);
        int xk = (keyb & 3) | ((keyb >> 1) & 12);
        f32x4 acc = f32x4{0.f, 0.f, 0.f, 0.f};
#pragma unroll
        for (int kst = 0; kst < 4; ++kst) {
          bf16x8 kb = *(const bf16x8*)&KL[keyb * 128 + (((kst * 4 + hi) ^ xk) * 8)];
          acc = __builtin_amdgcn_mfma_f32_16x16x32_bf16(kb, qf[kst], acc, 0, 0, 0);
        }
#pragma unroll
        for (int r = 0; r < 4; ++r) {
          int key = (jt & 1) * 32 + ((jt >> 1) << 2) + (hi << 3) + r;
          bool ok = rowsel && (!edge || (s * 64 + key) <= rowg);
          pv[jt * 4 + r] = ok ? acc[r] : -3.0e38f;
        }
      }
      // --- softmax: lane holds 16 vals of row cl; partners at lane^16, lane^32
      float mx = pv[0];
#pragma unroll
      for (int i = 1; i < 16; ++i) mx = fmaxf(mx, pv[i]);
      mx = fmaxf(mx, __shfl_xor(mx, 16));
      mx = fmaxf(mx, __shfl_xor(mx, 32));
      float mn = fmaxf(mrun, mx);
      float psum = 0.f;
#pragma unroll
      for (int i = 0; i < 16; ++i) {
        float e = exp2f_fast(pv[i] - mn);
        pv[i] = e;
        psum += e;
      }
      psum += __shfl_xor(psum, 16);
      psum += __shfl_xor(psum, 32);
      float alpha = exp2f_fast(mrun - mn);
      lrun = lrun * alpha + psum;
      mrun = mn;
#pragma unroll
      for (int i = 0; i < 8; ++i) oacc[i] *= alpha;
      // --- P^T B-frags: free transpose via keymap (pure register pack)
      bf16x8 pf[2];
#pragma unroll
      for (int kst = 0; kst < 2; ++kst) {
        union { bf16x8 v; unsigned short u[8]; } t;
#pragma unroll
        for (int j = 0; j < 4; ++j) {
          t.u[j] = f2bf(pv[kst * 4 + j]);
          t.u[4 + j] = f2bf(pv[(kst + 2) * 4 + j]);
        }
        pf[kst] = t.v;
      }
      // --- PV (swapped: A=V^T, B=P^T) -> oacc[ct][r] = O[row cl][d=ct*16+4hi+r]
#pragma unroll
      for (int ct = 0; ct < 8; ++ct) {
        int d = ct * 16 + cl;
#pragma unroll
        for (int kst = 0; kst < 2; ++kst) {
          bf16x8 vb = *(const bf16x8*)&VL[d * 64 + (((kst * 4 + hi) ^ (d & 7)) * 8)];
          oacc[ct] = __builtin_amdgcn_mfma_f32_16x16x32_bf16(vb, pf[kst], oacc[ct], 0, 0, 0);
        }
      }
    }
    asm volatile("" ::: "memory");
    __builtin_amdgcn_s_barrier();
    cur ^= 1;
    s = ns;
  }
  // --- epilogue
  float inv = 1.f / lrun;
  float* op = out + ((size_t)rowg * 32 + h) * 128;
#pragma unroll
  for (int ct = 0; ct < 8; ++ct) {
    f32x4 o4 = oacc[ct] * inv;
    *(float4*)&op[ct * 16 + hi * 4] = *(float4*)&o4;
  }
}

extern "C" void kernel_launch(void* const* d_in, const int* in_sizes, int n_in,
                              void* d_out, int out_size, void* d_ws, size_t ws_size,
                              hipStream_t stream) {
  const float* q = (const float*)d_in[0];
  const float* k = (const float*)d_in[1];
  const float* v = (const float*)d_in[2];
  const float* p = (const float*)d_in[3];
  float* out = (float*)d_out;
  // ws: [0,4MB) Vt bf16 [kv][d][pos]; [4MB,8MB) Kb bf16 [kv][pos][d]; [8MB,+64KB) selmask
  unsigned short* Vt = (unsigned short*)d_ws;
  unsigned short* Kb = (unsigned short*)((char*)d_ws + (size_t)4 * 1024 * 1024);
  unsigned* sm = (unsigned*)((char*)d_ws + (size_t)8 * 1024 * 1024);

  kconv_kernel<<<1024, 256, 0, stream>>>(k, Kb);
  vtrans_kernel<<<dim3(32, 8), 256, 0, stream>>>(v, Vt);
  sel_kernel<<<4096, 256, 0, stream>>>(p, sm);
  attn_kernel<<<dim3(128, 4), 512, 0, stream>>>(Kb, Vt, q, sm, out);
}

// Round 4
// 113.133 us; speedup vs baseline: 2.1821x; 1.3356x over previous
//
#include <hip/hip_runtime.h>

typedef __bf16 bf16x8 __attribute__((ext_vector_type(8)));
typedef float f32x4 __attribute__((ext_vector_type(4)));

__device__ __forceinline__ unsigned short f2bf(float x) {
  union { float f; unsigned u; } a; a.f = x;
  unsigned r = a.u + 0x7FFFu + ((a.u >> 16) & 1u);
  return (unsigned short)(r >> 16);
}

__device__ __forceinline__ float exp2f_fast(float x) {
  return __builtin_amdgcn_exp2f(x);  // v_exp_f32: 2^x
}

__device__ __forceinline__ unsigned cvtpk_bf16(float lo, float hi) {
  unsigned r;
  asm("v_cvt_pk_bf16_f32 %0, %1, %2" : "=v"(r) : "v"(lo), "v"(hi));
  return r;
}

__device__ __forceinline__ void gl_lds16(const void* g, void* l) {
  __builtin_amdgcn_global_load_lds(
      (const __attribute__((address_space(1))) void*)g,
      (__attribute__((address_space(3))) void*)l, 16, 0, 0);
}

// ---------------------------------------------------------------------------
// k (fp32 [pos][kv][d]) -> Kb bf16 [kv][pos][d]
// ---------------------------------------------------------------------------
__global__ __launch_bounds__(256) void kconv_kernel(const float* __restrict__ k,
                                                    unsigned short* __restrict__ Kb) {
  int t = blockIdx.x * 256 + threadIdx.x;
  int o = t * 8;
  int kv = o >> 18;
  int pos = (o >> 7) & 2047;
  int d = o & 127;
  const float* src = k + ((size_t)pos * 8 + kv) * 128 + d;
  float4 a = *(const float4*)src;
  float4 b = *(const float4*)(src + 4);
  union { bf16x8 v; unsigned short u[8]; } w;
  w.u[0] = f2bf(a.x); w.u[1] = f2bf(a.y); w.u[2] = f2bf(a.z); w.u[3] = f2bf(a.w);
  w.u[4] = f2bf(b.x); w.u[5] = f2bf(b.y); w.u[6] = f2bf(b.z); w.u[7] = f2bf(b.w);
  *(bf16x8*)&Kb[o] = w.v;
}

// ---------------------------------------------------------------------------
// v (fp32 [pos][kv][d]) -> Vt bf16 [kv][d][pos]
// ---------------------------------------------------------------------------
__global__ __launch_bounds__(256) void vtrans_kernel(const float* __restrict__ v,
                                                     unsigned short* __restrict__ Vt) {
  const int sblk = blockIdx.x, kv = blockIdx.y;
  __shared__ float T[64 * 128];
  const int t = threadIdx.x;
  for (int j = 0; j < 8; ++j) {
    int f4 = j * 256 + t;
    int pos = f4 >> 5;
    int doff = (f4 & 31) * 4;
    float4 src = *(const float4*)&v[(((size_t)(sblk * 64 + pos)) * 8 + kv) * 128 + doff];
    *(float4*)&T[pos * 128 + doff] = src;
  }
  __syncthreads();
  const int d = t >> 1, ph = t & 1;
  unsigned short tmp[32];
#pragma unroll
  for (int i = 0; i < 32; ++i) tmp[i] = f2bf(T[(ph * 32 + i) * 128 + d]);
  size_t base = ((size_t)kv * 128 + d) * 2048 + sblk * 64 + ph * 32;
#pragma unroll
  for (int c = 0; c < 4; ++c) {
    uint4 u;
    u.x = (unsigned)tmp[c * 8 + 0] | ((unsigned)tmp[c * 8 + 1] << 16);
    u.y = (unsigned)tmp[c * 8 + 2] | ((unsigned)tmp[c * 8 + 3] << 16);
    u.z = (unsigned)tmp[c * 8 + 4] | ((unsigned)tmp[c * 8 + 5] << 16);
    u.w = (unsigned)tmp[c * 8 + 6] | ((unsigned)tmp[c * 8 + 7] << 16);
    *(uint4*)&Vt[base + c * 8] = u;
  }
}

// ---------------------------------------------------------------------------
// Selection: one wave per (kv, m). Emits uint32 bitmask of selected blocks.
// ---------------------------------------------------------------------------
__global__ __launch_bounds__(256) void sel_kernel(const float* __restrict__ p,
                                                  unsigned* __restrict__ sm) {
  const int wid = blockIdx.x * 4 + (threadIdx.x >> 6);
  const int lane = threadIdx.x & 63;
  const int kv = wid >> 11;
  const int m = wid & 2047;
  const int rb = m >> 6;
  const int s = lane & 31;
  const int c0 = 4 * s - 1;
  float best = -1.f;
  for (int g = 0; g < 2; ++g) {
    int h = kv * 4 + (lane >> 5) * 2 + g;
    const float* pr = p + ((size_t)h * 2048 + m) * 127;
    float acc = 0.f;
    if (c0 >= 0) acc = fmaf(pr[c0], 1.f, acc);
    acc = fmaf(pr[c0 + 1], 2.f, acc);
    acc = fmaf(pr[c0 + 2], 2.f, acc);
    acc = fmaf(pr[c0 + 3], 2.f, acc);
    if (c0 + 4 < 127) acc = fmaf(pr[c0 + 4], 1.f, acc);
    best = fmaxf(best, acc);
  }
  best = fmaxf(best, __shfl_xor(best, 32));
  const int rbm1 = rb > 0 ? rb - 1 : 0;
  if (s == 0 || s == rb || s == rbm1) best = 999999.0f;
  const int kmax = min(rb + 1, 16);
  unsigned msk = 0;
  float val = best;
  for (int it = 0; it < kmax; ++it) {
    float v = val; int idx = s;
#pragma unroll
    for (int off = 1; off < 32; off <<= 1) {
      float ov = __shfl_xor(v, off);
      int oi = __shfl_xor(idx, off);
      if (ov > v || (ov == v && oi < idx)) { v = ov; idx = oi; }
    }
    msk |= (1u << idx);
    if (s == idx) val = -2.f;
  }
  if (lane == 0) sm[(size_t)kv * 2048 + m] = msk;
}

// ---------------------------------------------------------------------------
// Attention: WG = 128 rows (2 rb-tiles) x 1 head, 8 waves x 16 rows.
// z-mapping pairs (id, id+256) as (15-xi, xi): every CU's pair sums to 34
// stages -> flat load profile, no tail.
// ---------------------------------------------------------------------------
__global__ __launch_bounds__(512, 4) void attn_kernel(
    const unsigned short* __restrict__ Kb,
    const unsigned short* __restrict__ Vt,
    const float* __restrict__ q,
    const unsigned* __restrict__ sm,
    float* __restrict__ out) {
  const int kv = blockIdx.x & 7;
  const int xi = blockIdx.x >> 3;
  const int z = (blockIdx.y & 2) ? xi : (15 - xi);  // pair-balanced LPT
  const int h = kv * 4 + blockIdx.y;
  const int m0 = z * 128;
  const int tid = threadIdx.x;
  const int w = tid >> 6, lane = tid & 63;
  const int cl = lane & 15, hi = lane >> 4;
  const int rowg = m0 + w * 16 + cl;
  const int myrb = (m0 + w * 16) >> 6;
  const int rbU = 2 * z + 1;

  __shared__ unsigned short Klds[2][64 * 128];  // [key][d], chunk16 ^ x(key)
  __shared__ unsigned short Vlds[2][128 * 64];  // [d][pos], chunk8 ^ (d&7)
  __shared__ unsigned Ush;

  const float qs = 0.08838834764831845f * 1.4426950408889634f;
  bf16x8 qf[4];
  {
    const float* qp = q + ((size_t)rowg * 32 + h) * 128 + hi * 8;
#pragma unroll
    for (int kst = 0; kst < 4; ++kst) {
      float4 a = *(const float4*)(qp + kst * 32);
      float4 b = *(const float4*)(qp + kst * 32 + 4);
      union { bf16x8 v; unsigned short u[8]; } t;
      t.u[0] = f2bf(a.x * qs); t.u[1] = f2bf(a.y * qs); t.u[2] = f2bf(a.z * qs); t.u[3] = f2bf(a.w * qs);
      t.u[4] = f2bf(b.x * qs); t.u[5] = f2bf(b.y * qs); t.u[6] = f2bf(b.z * qs); t.u[7] = f2bf(b.w * qs);
      qf[kst] = t.v;
    }
  }
  unsigned selmask = sm[(size_t)kv * 2048 + rowg];
  unsigned uW = selmask;
#pragma unroll
  for (int off = 1; off < 16; off <<= 1) uW |= __shfl_xor(uW, off);
  if (tid == 0) Ush = 0;
  __syncthreads();
  if (lane == 0) atomicOr(&Ush, uW);
  __syncthreads();
  const unsigned U = Ush & ((2u << rbU) - 1u);
  const unsigned aW = uW & ((2u << myrb) - 1u);

  auto STAGE = [&](int b, int s) {
#pragma unroll
    for (int pass = 0; pass < 2; ++pass) {
      int cid = pass * 512 + w * 64 + lane;
      int key = cid >> 4, c = cid & 15;
      int xk = (key & 3) | ((key >> 1) & 12);
      gl_lds16(Kb + (size_t)(kv * 2048 + s * 64 + key) * 128 + ((c ^ xk) * 8),
               &Klds[b][(pass * 512 + w * 64) * 8]);
    }
#pragma unroll
    for (int pass = 0; pass < 2; ++pass) {
      int cid = pass * 512 + w * 64 + lane;
      int d = cid >> 3, c = cid & 7;
      gl_lds16(Vt + (size_t)(kv * 128 + d) * 2048 + s * 64 + ((c ^ (d & 7)) * 8),
               &Vlds[b][(pass * 512 + w * 64) * 8]);
    }
  };

  f32x4 oacc[8];
#pragma unroll
  for (int i = 0; i < 8; ++i) oacc[i] = f32x4{0.f, 0.f, 0.f, 0.f};
  float mrun = -3.0e38f, lrun = 0.f;

  int s = 0;
  int cur = 0;
  STAGE(0, 0);
  while (s >= 0) {
    int ns = -1;
    if (s < 31) {
      unsigned rest = U >> (s + 1);
      if (rest) ns = s + 1 + __builtin_ctz(rest);
    }
    if (ns >= 0) {
      STAGE(cur ^ 1, ns);
      asm volatile("s_waitcnt vmcnt(4)" ::: "memory");
    } else {
      asm volatile("s_waitcnt vmcnt(0)" ::: "memory");
    }
    __builtin_amdgcn_s_barrier();
    asm volatile("" ::: "memory");
    if ((s <= myrb) && ((aW >> s) & 1u)) {
      const unsigned short* KL = &Klds[cur][0];
      const unsigned short* VL = &Vlds[cur][0];
      // --- QK^T (swapped: A=K, B=Q)
      float pv[16];
      int lim = ((selmask >> s) & 1u) ? 63 : -1;  // key <= lim is live
      if (s == myrb) lim = min(lim, rowg - s * 64);
#pragma unroll
      for (int jt = 0; jt < 4; ++jt) {
        int keyb = (jt & 1) * 32 + ((jt >> 1) << 2) + ((cl >> 2) << 3) + (cl & 3);
        int xk = (keyb & 3) | ((keyb >> 1) & 12);
        f32x4 acc = f32x4{0.f, 0.f, 0.f, 0.f};
#pragma unroll
        for (int kst = 0; kst < 4; ++kst) {
          bf16x8 kb = *(const bf16x8*)&KL[keyb * 128 + (((kst * 4 + hi) ^ xk) * 8)];
          acc = __builtin_amdgcn_mfma_f32_16x16x32_bf16(kb, qf[kst], acc, 0, 0, 0);
        }
        int kb0 = (jt & 1) * 32 + ((jt >> 1) << 2) + (hi << 3);
#pragma unroll
        for (int r = 0; r < 4; ++r)
          pv[jt * 4 + r] = (kb0 + r <= lim) ? acc[r] : -3.0e38f;
      }
      // --- row max: tree (clang fuses to v_max3), partners at lane^16, lane^32
      float a0 = fmaxf(pv[0], pv[1]),  a1 = fmaxf(pv[2], pv[3]);
      float a2 = fmaxf(pv[4], pv[5]),  a3 = fmaxf(pv[6], pv[7]);
      float a4 = fmaxf(pv[8], pv[9]),  a5 = fmaxf(pv[10], pv[11]);
      float a6 = fmaxf(pv[12], pv[13]), a7 = fmaxf(pv[14], pv[15]);
      float mx = fmaxf(fmaxf(fmaxf(a0, a1), fmaxf(a2, a3)),
                       fmaxf(fmaxf(a4, a5), fmaxf(a6, a7)));
      mx = fmaxf(mx, __shfl_xor(mx, 16));
      mx = fmaxf(mx, __shfl_xor(mx, 32));
      const bool stay = __all(mx <= mrun);  // exact: alpha == 1
      float mn = stay ? mrun : fmaxf(mrun, mx);
#pragma unroll
      for (int i = 0; i < 16; ++i) pv[i] = exp2f_fast(pv[i] - mn);
      float s0 = (pv[0] + pv[1]) + (pv[2] + pv[3]);
      float s1 = (pv[4] + pv[5]) + (pv[6] + pv[7]);
      float s2 = (pv[8] + pv[9]) + (pv[10] + pv[11]);
      float s3 = (pv[12] + pv[13]) + (pv[14] + pv[15]);
      float psum = (s0 + s1) + (s2 + s3);
      psum += __shfl_xor(psum, 16);
      psum += __shfl_xor(psum, 32);
      if (stay) {
        lrun += psum;
      } else {
        float alpha = exp2f_fast(mrun - mn);
        lrun = lrun * alpha + psum;
        mrun = mn;
#pragma unroll
        for (int i = 0; i < 8; ++i) oacc[i] *= alpha;
      }
      // --- P^T B-frags via v_cvt_pk_bf16_f32 (8 ops for 16 values)
      bf16x8 pf[2];
#pragma unroll
      for (int kst = 0; kst < 2; ++kst) {
        union { bf16x8 v; unsigned w4[4]; } t;
        t.w4[0] = cvtpk_bf16(pv[kst * 4 + 0], pv[kst * 4 + 1]);
        t.w4[1] = cvtpk_bf16(pv[kst * 4 + 2], pv[kst * 4 + 3]);
        t.w4[2] = cvtpk_bf16(pv[(kst + 2) * 4 + 0], pv[(kst + 2) * 4 + 1]);
        t.w4[3] = cvtpk_bf16(pv[(kst + 2) * 4 + 2], pv[(kst + 2) * 4 + 3]);
        pf[kst] = t.v;
      }
      // --- PV (swapped: A=V^T, B=P^T)
#pragma unroll
      for (int ct = 0; ct < 8; ++ct) {
        int d = ct * 16 + cl;
#pragma unroll
        for (int kst = 0; kst < 2; ++kst) {
          bf16x8 vb = *(const bf16x8*)&VL[d * 64 + (((kst * 4 + hi) ^ (d & 7)) * 8)];
          oacc[ct] = __builtin_amdgcn_mfma_f32_16x16x32_bf16(vb, pf[kst], oacc[ct], 0, 0, 0);
        }
      }
    }
    asm volatile("" ::: "memory");
    __builtin_amdgcn_s_barrier();
    cur ^= 1;
    s = ns;
  }
  float inv = 1.f / lrun;
  float* op = out + ((size_t)rowg * 32 + h) * 128;
#pragma unroll
  for (int ct = 0; ct < 8; ++ct) {
    f32x4 o4 = oacc[ct] * inv;
    *(float4*)&op[ct * 16 + hi * 4] = *(float4*)&o4;
  }
}

extern "C" void kernel_launch(void* const* d_in, const int* in_sizes, int n_in,
                              void* d_out, int out_size, void* d_ws, size_t ws_size,
                              hipStream_t stream) {
  const float* q = (const float*)d_in[0];
  const float* k = (const float*)d_in[1];
  const float* v = (const float*)d_in[2];
  const float* p = (const float*)d_in[3];
  float* out = (float*)d_out;
  unsigned short* Vt = (unsigned short*)d_ws;
  unsigned short* Kb = (unsigned short*)((char*)d_ws + (size_t)4 * 1024 * 1024);
  unsigned* sm = (unsigned*)((char*)d_ws + (size_t)8 * 1024 * 1024);

  kconv_kernel<<<1024, 256, 0, stream>>>(k, Kb);
  vtrans_kernel<<<dim3(32, 8), 256, 0, stream>>>(v, Vt);
  sel_kernel<<<4096, 256, 0, stream>>>(p, sm);
  attn_kernel<<<dim3(128, 4), 512, 0, stream>>>(Kb, Vt, q, sm, out);
}

// Round 5
// 87.715 us; speedup vs baseline: 2.8145x; 1.2898x over previous
//
#include <hip/hip_runtime.h>

typedef __bf16 bf16x8 __attribute__((ext_vector_type(8)));
typedef float f32x4 __attribute__((ext_vector_type(4)));
typedef float f32x16 __attribute__((ext_vector_type(16)));

__device__ __forceinline__ unsigned short f2bf(float x) {
  union { float f; unsigned u; } a; a.f = x;
  unsigned r = a.u + 0x7FFFu + ((a.u >> 16) & 1u);
  return (unsigned short)(r >> 16);
}

__device__ __forceinline__ float exp2f_fast(float x) {
  return __builtin_amdgcn_exp2f(x);
}

__device__ __forceinline__ unsigned cvtpk_bf16(float lo, float hi) {
  unsigned r;
  asm("v_cvt_pk_bf16_f32 %0, %1, %2" : "=v"(r) : "v"(lo), "v"(hi));
  return r;
}

__device__ __forceinline__ void gl_lds16(const void* g, void* l) {
  __builtin_amdgcn_global_load_lds(
      (const __attribute__((address_space(1))) void*)g,
      (__attribute__((address_space(3))) void*)l, 16, 0, 0);
}

__device__ __forceinline__ int swap23(int x) {  // swap bits 2 and 3
  return (x & ~12) | ((x & 4) << 1) | ((x & 8) >> 1);
}

// ---------------------------------------------------------------------------
// Fused prep: [0,4096) sel | [4096,5120) kconv | [5120,6144) vtrans
// ---------------------------------------------------------------------------
__global__ __launch_bounds__(256) void prep_kernel(const float* __restrict__ k,
                                                   const float* __restrict__ v,
                                                   const float* __restrict__ p,
                                                   unsigned short* __restrict__ Kb,
                                                   unsigned short* __restrict__ Vt,
                                                   unsigned* __restrict__ sm) {
  const int bx = blockIdx.x;
  if (bx < 4096) {
    // --- selection, rank-based top-k (one wave per (kv, m))
    const int wid = bx * 4 + (threadIdx.x >> 6);
    const int lane = threadIdx.x & 63;
    const int kv = wid >> 11;
    const int m = wid & 2047;
    const int rb = m >> 6;
    const int s = lane & 31;
    const int c0 = 4 * s - 1;
    float best = -1.f;
    for (int g = 0; g < 2; ++g) {
      int h = kv * 4 + (lane >> 5) * 2 + g;
      const float* pr = p + ((size_t)h * 2048 + m) * 127;
      float acc = 0.f;
      if (c0 >= 0) acc = fmaf(pr[c0], 1.f, acc);
      acc = fmaf(pr[c0 + 1], 2.f, acc);
      acc = fmaf(pr[c0 + 2], 2.f, acc);
      acc = fmaf(pr[c0 + 3], 2.f, acc);
      if (c0 + 4 < 127) acc = fmaf(pr[c0 + 4], 1.f, acc);
      best = fmaxf(best, acc);
    }
    best = fmaxf(best, __shfl_xor(best, 32));  // max over the 4 heads of group
    const int rbm1 = rb > 0 ? rb - 1 : 0;
    if (s == 0 || s == rb || s == rbm1) best = 999999.0f;  // KEEP
    // rank(s) = #{j : v[j] > v[s] || (v[j]==v[s] && j < s)}; halves split offsets
    const int half = lane & 32;
    int cnt = 0;
#pragma unroll
    for (int o = 1; o <= 16; ++o) {
      int oo = half ? (o + 16) : o;          // low: 1..16, high: 17..32(skip 32)
      int os = (s + oo) & 31;
      float ov = __shfl(best, half | os);
      bool gr = (ov > best) || (ov == best && os < s);
      cnt += (gr && oo < 32) ? 1 : 0;
    }
    int rank = cnt + __shfl_xor(cnt, 32);
    const int kmax = min(rb + 1, 16);
    unsigned long long bal = __ballot(rank < kmax);
    if (lane == 0) sm[(size_t)kv * 2048 + m] = (unsigned)(bal & 0xffffffffu);
  } else if (bx < 5120) {
    // --- k (fp32 [pos][kv][d]) -> Kb bf16 [kv][pos][d]
    int t = (bx - 4096) * 256 + threadIdx.x;
    int o = t * 8;
    int kv = o >> 18;
    int pos = (o >> 7) & 2047;
    int d = o & 127;
    const float* src = k + ((size_t)pos * 8 + kv) * 128 + d;
    float4 a = *(const float4*)src;
    float4 b = *(const float4*)(src + 4);
    union { bf16x8 v; unsigned short u[8]; } w;
    w.u[0] = f2bf(a.x); w.u[1] = f2bf(a.y); w.u[2] = f2bf(a.z); w.u[3] = f2bf(a.w);
    w.u[4] = f2bf(b.x); w.u[5] = f2bf(b.y); w.u[6] = f2bf(b.z); w.u[7] = f2bf(b.w);
    *(bf16x8*)&Kb[o] = w.v;
  } else {
    // --- v (fp32 [pos][kv][d]) -> Vt bf16 [kv][d][pos], 16-pos slabs
    __shared__ float T[16 * 128];
    const int vb = bx - 5120;
    const int sb = vb >> 3, kvv = vb & 7;
    const int t = threadIdx.x;
    {
      int pos = t >> 4, dof = (t & 15) * 8;
      const float* src = v + ((size_t)(sb * 16 + pos) * 8 + kvv) * 128 + dof;
      float4 a = *(const float4*)src;
      float4 b = *(const float4*)(src + 4);
      *(float4*)&T[pos * 128 + dof] = a;
      *(float4*)&T[pos * 128 + dof + 4] = b;
    }
    __syncthreads();
    {
      int d = t >> 1, ph = t & 1;
      unsigned short u8[8];
#pragma unroll
      for (int i = 0; i < 8; ++i) u8[i] = f2bf(T[(ph * 8 + i) * 128 + d]);
      uint4 uu;
      uu.x = (unsigned)u8[0] | ((unsigned)u8[1] << 16);
      uu.y = (unsigned)u8[2] | ((unsigned)u8[3] << 16);
      uu.z = (unsigned)u8[4] | ((unsigned)u8[5] << 16);
      uu.w = (unsigned)u8[6] | ((unsigned)u8[7] << 16);
      *(uint4*)&Vt[((size_t)kvv * 128 + d) * 2048 + sb * 16 + ph * 8] = uu;
    }
  }
}

// ---------------------------------------------------------------------------
// Attention: WG = 32 rows x ALL 4 heads of a kv-group (they share selection).
// 4 waves x (8 rows x 4 heads = N-dim 32). 32x32x16 MFMA (2x FLOP per LDS read).
// K rows stored with bit2<->bit3 keymap -> QK acc is pos-ascending per lane ->
// P pack for PV B-frag is 16 sequential cvt_pk (no cross-lane traffic).
// grid 512 = 64 z x 8 kv; pair (wg, wg+256) sums to 33 stages on every CU.
// ---------------------------------------------------------------------------
__global__ __launch_bounds__(256, 2) void attn_kernel(
    const unsigned short* __restrict__ Kb,
    const unsigned short* __restrict__ Vt,
    const float* __restrict__ q,
    const unsigned* __restrict__ sm,
    float* __restrict__ out) {
  const int wg = blockIdx.x;
  const int kv = wg & 7;                       // kv aligned to XCD
  const int zi = wg >> 3;
  const int z = (zi < 32) ? (2 * zi + 1) : (126 - 2 * zi);  // pair-balanced
  const int m0 = z * 32;
  const int rb = z >> 1;
  const int tid = threadIdx.x;
  const int w = tid >> 6, lane = tid & 63;
  const int c = lane & 31, hb = lane >> 5;
  const int ro = c & 7, h4 = c >> 3;
  const int row = m0 + w * 8 + ro;
  const int head = kv * 4 + h4;

  __shared__ unsigned short Klds[2][64 * 128];  // [lrow][d], keymapped rows
  __shared__ unsigned short Vlds[2][128 * 64];  // [d][pos]
  __shared__ unsigned Ush;

  // Q B-frags: B[k][col], col = h4*8+ro, k = 16*ks + 8*hb + i
  const float qs = 0.08838834764831845f * 1.4426950408889634f;
  bf16x8 qf[8];
  {
    const float* qp = q + ((size_t)row * 32 + head) * 128 + hb * 8;
#pragma unroll
    for (int ks = 0; ks < 8; ++ks) {
      float4 a = *(const float4*)(qp + ks * 16);
      float4 b = *(const float4*)(qp + ks * 16 + 4);
      union { bf16x8 v; unsigned short u[8]; } t;
      t.u[0] = f2bf(a.x * qs); t.u[1] = f2bf(a.y * qs); t.u[2] = f2bf(a.z * qs); t.u[3] = f2bf(a.w * qs);
      t.u[4] = f2bf(b.x * qs); t.u[5] = f2bf(b.y * qs); t.u[6] = f2bf(b.z * qs); t.u[7] = f2bf(b.w * qs);
      qf[ks] = t.v;
    }
  }
  unsigned selr = sm[(size_t)kv * 2048 + row];
  unsigned uW = selr;                           // union over wave's 8 rows
  uW |= __shfl_xor(uW, 1); uW |= __shfl_xor(uW, 2); uW |= __shfl_xor(uW, 4);
  if (tid == 0) Ush = 0;
  __syncthreads();
  if (lane == 0) atomicOr(&Ush, uW);
  __syncthreads();
  const unsigned cmask = (2u << rb) - 1u;       // rb=31 wraps to 0xffffffff
  const unsigned U = Ush & cmask;
  const unsigned aW = uW & cmask;

  // stage K (keymapped rows + chunk swizzle) and V^T into buffer b
  auto STAGE = [&](int b, int si) {
#pragma unroll
    for (int pS = 0; pS < 4; ++pS) {
      int cid = (pS * 4 + w) * 64 + lane;
      int lrow = cid >> 4, pc = cid & 15;
      int pos = swap23(lrow);
      int xk = (lrow & 3) | ((lrow >> 1) & 12);
      gl_lds16(Kb + (((size_t)(kv * 2048 + si * 64 + pos)) << 7) + ((pc ^ xk) << 3),
               &Klds[b][(pS * 4 + w) * 512]);
    }
#pragma unroll
    for (int pS = 0; pS < 4; ++pS) {
      int cid = (pS * 4 + w) * 64 + lane;
      int d = cid >> 3, c8 = cid & 7;
      gl_lds16(Vt + ((size_t)(kv * 128 + d) << 11) + si * 64 + ((c8 ^ (d & 7)) << 3),
               &Vlds[b][(pS * 4 + w) * 512]);
    }
  };

  f32x16 oacc[4];
#pragma unroll
  for (int i = 0; i < 4; ++i)
#pragma unroll
    for (int e = 0; e < 16; ++e) oacc[i][e] = 0.f;
  float mrun = -3.0e38f, lrun = 0.f;

  int s = 0;  // bit 0 of U always set (block 0 forced for every row)
  int cur = 0;
  STAGE(0, 0);
  while (s >= 0) {
    int ns = -1;
    if (s < 31) {
      unsigned rest = U >> (s + 1);
      if (rest) ns = s + 1 + __builtin_ctz(rest);
    }
    if (ns >= 0) {
      STAGE(cur ^ 1, ns);
      asm volatile("s_waitcnt vmcnt(8)" ::: "memory");  // current buf complete
    } else {
      asm volatile("s_waitcnt vmcnt(0)" ::: "memory");
    }
    __builtin_amdgcn_s_barrier();
    asm volatile("" ::: "memory");
    if ((aW >> s) & 1u) {
      const unsigned short* KL = &Klds[cur][0];
      const unsigned short* VL = &Vlds[cur][0];
      // --- QK^T: A = K (32 keys x 16k), B = Q. acc[kb][r] is pos-ascending.
      const int xk = (c & 3) | ((c >> 1) & 12);
      f32x16 acc0 = {}, acc1 = {};
#pragma unroll
      for (int ks = 0; ks < 8; ++ks) {
        bf16x8 k0 = *(const bf16x8*)&KL[c * 128 + (((2 * ks + hb) ^ xk) << 3)];
        acc0 = __builtin_amdgcn_mfma_f32_32x32x16_bf16(k0, qf[ks], acc0, 0, 0, 0);
      }
#pragma unroll
      for (int ks = 0; ks < 8; ++ks) {
        bf16x8 k1 = *(const bf16x8*)&KL[(32 + c) * 128 + (((2 * ks + hb) ^ xk) << 3)];
        acc1 = __builtin_amdgcn_mfma_f32_32x32x16_bf16(k1, qf[ks], acc1, 0, 0, 0);
      }
      // --- mask: pv[j] holds pos = (j>>4)*32 + ((j>>3)&1)*16 + 8*hb + (j&7)
      int lim = ((selr >> s) & 1u) ? ((s == rb) ? (row & 63) : 63) : -1;
      int limadj = lim - 8 * hb;
      float pv[32];
#pragma unroll
      for (int j = 0; j < 32; ++j) {
        int P0 = ((j >> 4) << 5) + (((j >> 3) & 1) << 4) + (j & 7);
        float x = (j < 16) ? acc0[j & 15] : acc1[j & 15];
        pv[j] = (P0 <= limadj) ? x : -3.0e38f;
      }
      // --- row-head max (tree) ; partner at lane^32
      float t0[8];
#pragma unroll
      for (int j = 0; j < 8; ++j)
        t0[j] = fmaxf(fmaxf(pv[4 * j], pv[4 * j + 1]), fmaxf(pv[4 * j + 2], pv[4 * j + 3]));
      float mx = fmaxf(fmaxf(fmaxf(t0[0], t0[1]), fmaxf(t0[2], t0[3])),
                       fmaxf(fmaxf(t0[4], t0[5]), fmaxf(t0[6], t0[7])));
      mx = fmaxf(mx, __shfl_xor(mx, 32));
      const bool stay = __all(mx <= mrun);   // exact: alpha == 1
      float mn = stay ? mrun : fmaxf(mrun, mx);
#pragma unroll
      for (int j = 0; j < 32; ++j) pv[j] = exp2f_fast(pv[j] - mn);
      float s0[8];
#pragma unroll
      for (int j = 0; j < 8; ++j)
        s0[j] = (pv[4 * j] + pv[4 * j + 1]) + (pv[4 * j + 2] + pv[4 * j + 3]);
      float psum = ((s0[0] + s0[1]) + (s0[2] + s0[3])) + ((s0[4] + s0[5]) + (s0[6] + s0[7]));
      psum += __shfl_xor(psum, 32);
      if (stay) {
        lrun += psum;
      } else {
        float alpha = exp2f_fast(mrun - mn);
        lrun = lrun * alpha + psum;
        mrun = mn;
#pragma unroll
        for (int i = 0; i < 4; ++i) oacc[i] *= alpha;
      }
      // --- P B-frags: pf[kk].u16[i] = bf16(pv[8kk+i]) (pos-sequential)
      bf16x8 pf[4];
#pragma unroll
      for (int kk = 0; kk < 4; ++kk) {
        union { bf16x8 v; unsigned w4[4]; } t;
        t.w4[0] = cvtpk_bf16(pv[8 * kk + 0], pv[8 * kk + 1]);
        t.w4[1] = cvtpk_bf16(pv[8 * kk + 2], pv[8 * kk + 3]);
        t.w4[2] = cvtpk_bf16(pv[8 * kk + 4], pv[8 * kk + 5]);
        t.w4[3] = cvtpk_bf16(pv[8 * kk + 6], pv[8 * kk + 7]);
        pf[kk] = t.v;
      }
      // --- PV: A = V^T (32 d x 16 pos), B = P^T
#pragma unroll
      for (int db = 0; db < 4; ++db) {
        int d = db * 32 + c;
        int xv = d & 7;
#pragma unroll
        for (int kk = 0; kk < 4; ++kk) {
          bf16x8 vf = *(const bf16x8*)&VL[(d << 6) + (((2 * kk + hb) ^ xv) << 3)];
          oacc[db] = __builtin_amdgcn_mfma_f32_32x32x16_bf16(vf, pf[kk], oacc[db], 0, 0, 0);
        }
      }
    }
    asm volatile("" ::: "memory");
    __builtin_amdgcn_s_barrier();
    cur ^= 1;
    s = ns;
  }
  // --- epilogue: O[row,head][d = db*32 + 8*rg + 4*hb + 0..3]
  float inv = 1.f / lrun;
  float* op = out + ((size_t)row * 32 + head) * 128;
#pragma unroll
  for (int db = 0; db < 4; ++db) {
#pragma unroll
    for (int rg = 0; rg < 4; ++rg) {
      float4 o4;
      o4.x = oacc[db][4 * rg + 0] * inv;
      o4.y = oacc[db][4 * rg + 1] * inv;
      o4.z = oacc[db][4 * rg + 2] * inv;
      o4.w = oacc[db][4 * rg + 3] * inv;
      *(float4*)&op[db * 32 + rg * 8 + hb * 4] = o4;
    }
  }
}

extern "C" void kernel_launch(void* const* d_in, const int* in_sizes, int n_in,
                              void* d_out, int out_size, void* d_ws, size_t ws_size,
                              hipStream_t stream) {
  const float* q = (const float*)d_in[0];
  const float* k = (const float*)d_in[1];
  const float* v = (const float*)d_in[2];
  const float* p = (const float*)d_in[3];
  float* out = (float*)d_out;
  unsigned short* Vt = (unsigned short*)d_ws;
  unsigned short* Kb = (unsigned short*)((char*)d_ws + (size_t)4 * 1024 * 1024);
  unsigned* sm = (unsigned*)((char*)d_ws + (size_t)8 * 1024 * 1024);

  prep_kernel<<<6144, 256, 0, stream>>>(k, v, p, Kb, Vt, sm);
  attn_kernel<<<512, 256, 0, stream>>>(Kb, Vt, q, sm, out);
}

// Round 6
// 70.779 us; speedup vs baseline: 3.4879x; 1.2393x over previous
//
#include <hip/hip_runtime.h>

typedef __bf16 bf16x8 __attribute__((ext_vector_type(8)));
typedef float f32x4 __attribute__((ext_vector_type(4)));
typedef float f32x16 __attribute__((ext_vector_type(16)));

__device__ __forceinline__ unsigned short f2bf(float x) {
  union { float f; unsigned u; } a; a.f = x;
  unsigned r = a.u + 0x7FFFu + ((a.u >> 16) & 1u);
  return (unsigned short)(r >> 16);
}

__device__ __forceinline__ float exp2f_fast(float x) {
  return __builtin_amdgcn_exp2f(x);
}

__device__ __forceinline__ unsigned cvtpk_bf16(float lo, float hi) {
  unsigned r;
  asm("v_cvt_pk_bf16_f32 %0, %1, %2" : "=v"(r) : "v"(lo), "v"(hi));
  return r;
}

__device__ __forceinline__ int swap23(int x) {  // swap bits 2 and 3
  return (x & ~12) | ((x & 4) << 1) | ((x & 8) >> 1);
}

// ---------------------------------------------------------------------------
// Fused prep.
//  [0,4096):    selection -> sm bitmasks
//  [4096,4352): K -> Kt fragment-tiled bf16: Kt[kv][s][j][lane] (16B slots)
//               j<8:  A-row c holds pos swap23(c),    d = 16j + 8hb
//               j>=8: A-row c holds pos 32+swap23(c), d = 16(j-8) + 8hb
//  [4352,4608): V -> Vt fragment-tiled bf16: Vt[kv][s][j'][lane]
//               j' = db*4+kk: lane (c,hb) holds V[s*64+16kk+8hb+i][db*32+c]
// ---------------------------------------------------------------------------
__global__ __launch_bounds__(256) void prep_kernel(const float* __restrict__ k,
                                                   const float* __restrict__ v,
                                                   const float* __restrict__ p,
                                                   unsigned short* __restrict__ Kt,
                                                   unsigned short* __restrict__ Vt,
                                                   unsigned* __restrict__ sm) {
  const int bx = blockIdx.x;
  if (bx < 4096) {
    // --- selection, rank-based top-k (one wave per (kv, m))
    const int wid = bx * 4 + (threadIdx.x >> 6);
    const int lane = threadIdx.x & 63;
    const int kv = wid >> 11;
    const int m = wid & 2047;
    const int rb = m >> 6;
    const int s = lane & 31;
    const int c0 = 4 * s - 1;
    float best = -1.f;
    for (int g = 0; g < 2; ++g) {
      int h = kv * 4 + (lane >> 5) * 2 + g;
      const float* pr = p + ((size_t)h * 2048 + m) * 127;
      float acc = 0.f;
      if (c0 >= 0) acc = fmaf(pr[c0], 1.f, acc);
      acc = fmaf(pr[c0 + 1], 2.f, acc);
      acc = fmaf(pr[c0 + 2], 2.f, acc);
      acc = fmaf(pr[c0 + 3], 2.f, acc);
      if (c0 + 4 < 127) acc = fmaf(pr[c0 + 4], 1.f, acc);
      best = fmaxf(best, acc);
    }
    best = fmaxf(best, __shfl_xor(best, 32));
    const int rbm1 = rb > 0 ? rb - 1 : 0;
    if (s == 0 || s == rb || s == rbm1) best = 999999.0f;
    const int half = lane & 32;
    int cnt = 0;
#pragma unroll
    for (int o = 1; o <= 16; ++o) {
      int oo = half ? (o + 16) : o;
      int os = (s + oo) & 31;
      float ov = __shfl(best, half | os);
      bool gr = (ov > best) || (ov == best && os < s);
      cnt += (gr && oo < 32) ? 1 : 0;
    }
    int rank = cnt + __shfl_xor(cnt, 32);
    const int kmax = min(rb + 1, 16);
    unsigned long long bal = __ballot(rank < kmax);
    if (lane == 0) sm[(size_t)kv * 2048 + m] = (unsigned)(bal & 0xffffffffu);
  } else if (bx < 4352) {
    // --- K fragment tiler
    const int kvs = bx - 4096;                 // kv*32 + s
    const int kv = kvs >> 5, s = kvs & 31;
    const int lane = threadIdx.x & 63;
    const int jg = threadIdx.x >> 6;
    const int c = lane & 31, hb = lane >> 5;
    const int posl = swap23(c);
    unsigned short* dst = Kt + ((size_t)kvs << 13);
#pragma unroll
    for (int jj = 0; jj < 4; ++jj) {
      int j = jg * 4 + jj;
      int pos = s * 64 + ((j >> 3) << 5) + posl;
      int d0 = ((j & 7) << 4) + (hb << 3);
      const float* src = k + (((size_t)pos * 8 + kv) << 7) + d0;
      float4 a = *(const float4*)src;
      float4 b = *(const float4*)(src + 4);
      union { bf16x8 w; unsigned short u[8]; } t;
      t.u[0] = f2bf(a.x); t.u[1] = f2bf(a.y); t.u[2] = f2bf(a.z); t.u[3] = f2bf(a.w);
      t.u[4] = f2bf(b.x); t.u[5] = f2bf(b.y); t.u[6] = f2bf(b.z); t.u[7] = f2bf(b.w);
      *(bf16x8*)(dst + ((j * 64 + lane) << 3)) = t.w;
    }
  } else {
    // --- V fragment tiler (transposed gather)
    const int kvs = bx - 4352;
    const int kv = kvs >> 5, s = kvs & 31;
    const int lane = threadIdx.x & 63;
    const int jg = threadIdx.x >> 6;
    const int c = lane & 31, hb = lane >> 5;
    unsigned short* dst = Vt + ((size_t)kvs << 13);
#pragma unroll
    for (int jj = 0; jj < 4; ++jj) {
      int j = jg * 4 + jj;
      int db = j >> 2, kk = j & 3;
      int d = (db << 5) + c;
      int pos0 = s * 64 + (kk << 4) + (hb << 3);
      union { bf16x8 w; unsigned short u[8]; } t;
#pragma unroll
      for (int i = 0; i < 8; ++i)
        t.u[i] = f2bf(v[(((size_t)(pos0 + i) * 8 + kv) << 7) + d]);
      *(bf16x8*)(dst + ((j * 64 + lane) << 3)) = t.w;
    }
  }
}

// ---------------------------------------------------------------------------
// Attention: barrier-free, LDS-free. Each wave = 8 rows x 4 heads (32 output
// cols), walks its own causal-selected block list, loading K/V fragments
// directly from the fragment-tiled L2-resident buffers (1KB coalesced loads).
// Fixed-reference softmax (m=0): no max tracking, no rescale, trivially
// correct merge-free accumulation. grid 512 = 64 z x 8 kv (kv == XCD).
// ---------------------------------------------------------------------------
__global__ __launch_bounds__(256, 2) void attn_kernel(
    const unsigned short* __restrict__ Kt,
    const unsigned short* __restrict__ Vt,
    const float* __restrict__ q,
    const unsigned* __restrict__ sm,
    float* __restrict__ out) {
  const int wg = blockIdx.x;
  const int kv = wg & 7;
  const int zi = wg >> 3;
  const int z = (zi < 32) ? (2 * zi + 1) : (126 - 2 * zi);  // pair-balanced
  const int m0 = z * 32;
  const int rb = z >> 1;
  const int tid = threadIdx.x;
  const int w = tid >> 6, lane = tid & 63;
  const int c = lane & 31, hb = lane >> 5;
  const int row = m0 + w * 8 + (c & 7);
  const int head = kv * 4 + (c >> 3);

  // Q B-frags (scale * log2e folded in): lane holds col (row,head), k=16ks+8hb+i
  const float qs = 0.08838834764831845f * 1.4426950408889634f;
  bf16x8 qf[8];
  {
    const float* qp = q + ((size_t)row * 32 + head) * 128 + hb * 8;
#pragma unroll
    for (int ks = 0; ks < 8; ++ks) {
      float4 a = *(const float4*)(qp + ks * 16);
      float4 b = *(const float4*)(qp + ks * 16 + 4);
      union { bf16x8 v; unsigned w4[4]; } t;
      t.w4[0] = cvtpk_bf16(a.x * qs, a.y * qs);
      t.w4[1] = cvtpk_bf16(a.z * qs, a.w * qs);
      t.w4[2] = cvtpk_bf16(b.x * qs, b.y * qs);
      t.w4[3] = cvtpk_bf16(b.z * qs, b.w * qs);
      qf[ks] = t.v;
    }
  }
  const unsigned selr = sm[(size_t)kv * 2048 + row];
  unsigned aW = selr;
  aW |= __shfl_xor(aW, 1);
  aW |= __shfl_xor(aW, 2);
  aW |= __shfl_xor(aW, 4);           // union over the wave's 8 rows
  aW &= (2u << rb) - 1u;             // causal cap (rb=31 wraps to all-ones)

  f32x16 oacc[4];
#pragma unroll
  for (int i = 0; i < 4; ++i)
#pragma unroll
    for (int e = 0; e < 16; ++e) oacc[i][e] = 0.f;
  float lrun = 0.f;

  const unsigned short* Kb = Kt + ((size_t)(kv * 32) << 13);
  const unsigned short* Vb = Vt + ((size_t)(kv * 32) << 13);

  unsigned bits = aW;
  while (bits) {
    const int s = __builtin_ctz(bits);
    bits &= bits - 1;
    const unsigned short* kt = Kb + ((size_t)s << 13);
    const unsigned short* vt = Vb + ((size_t)s << 13);
    // --- K fragments: 16 coalesced 1KB loads
    bf16x8 kf[16];
#pragma unroll
    for (int j = 0; j < 16; ++j)
      kf[j] = *(const bf16x8*)(kt + ((j * 64 + lane) << 3));
    // --- QK^T (swapped: A=K, B=Q); acc pos-ascending per lane via swap23 tiling
    f32x16 a0 = {}, a1 = {};
#pragma unroll
    for (int ks = 0; ks < 8; ++ks)
      a0 = __builtin_amdgcn_mfma_f32_32x32x16_bf16(kf[ks], qf[ks], a0, 0, 0, 0);
#pragma unroll
    for (int ks = 0; ks < 8; ++ks)
      a1 = __builtin_amdgcn_mfma_f32_32x32x16_bf16(kf[8 + ks], qf[ks], a1, 0, 0, 0);
    // --- V fragments issued now; latency hides under softmax VALU
    bf16x8 vf[16];
#pragma unroll
    for (int j = 0; j < 16; ++j)
      vf[j] = *(const bf16x8*)(vt + ((j * 64 + lane) << 3));
    // --- mask + exp (fixed reference m=0)
    int lim = ((selr >> s) & 1u) ? ((s == rb) ? (row & 63) : 63) : -1;
    int limadj = lim - 8 * hb;
    float pv[32];
#pragma unroll
    for (int j = 0; j < 32; ++j) {
      int P0 = ((j >> 4) << 5) + (((j >> 3) & 1) << 4) + (j & 7);
      float x = (j < 16) ? a0[j & 15] : a1[j & 15];
      pv[j] = exp2f_fast((P0 <= limadj) ? x : -3.0e38f);
    }
    float s0[8];
#pragma unroll
    for (int j = 0; j < 8; ++j)
      s0[j] = (pv[4 * j] + pv[4 * j + 1]) + (pv[4 * j + 2] + pv[4 * j + 3]);
    float psum = ((s0[0] + s0[1]) + (s0[2] + s0[3])) + ((s0[4] + s0[5]) + (s0[6] + s0[7]));
    psum += __shfl_xor(psum, 32);
    lrun += psum;
    // --- P B-frags: pos-sequential pack, 16 cvt_pk
    bf16x8 pf[4];
#pragma unroll
    for (int kk = 0; kk < 4; ++kk) {
      union { bf16x8 v; unsigned w4[4]; } t;
      t.w4[0] = cvtpk_bf16(pv[8 * kk + 0], pv[8 * kk + 1]);
      t.w4[1] = cvtpk_bf16(pv[8 * kk + 2], pv[8 * kk + 3]);
      t.w4[2] = cvtpk_bf16(pv[8 * kk + 4], pv[8 * kk + 5]);
      t.w4[3] = cvtpk_bf16(pv[8 * kk + 6], pv[8 * kk + 7]);
      pf[kk] = t.v;
    }
    // --- PV (swapped: A=V^T, B=P^T)
#pragma unroll
    for (int jp = 0; jp < 16; ++jp)
      oacc[jp >> 2] = __builtin_amdgcn_mfma_f32_32x32x16_bf16(vf[jp], pf[jp & 3], oacc[jp >> 2], 0, 0, 0);
  }
  // --- epilogue: O[row,head][d = db*32 + 8*rg + 4*hb + e]
  const float inv = 1.f / lrun;
  float* op = out + ((size_t)row * 32 + head) * 128;
#pragma unroll
  for (int db = 0; db < 4; ++db) {
#pragma unroll
    for (int rg = 0; rg < 4; ++rg) {
      float4 o4;
      o4.x = oacc[db][4 * rg + 0] * inv;
      o4.y = oacc[db][4 * rg + 1] * inv;
      o4.z = oacc[db][4 * rg + 2] * inv;
      o4.w = oacc[db][4 * rg + 3] * inv;
      *(float4*)&op[db * 32 + rg * 8 + hb * 4] = o4;
    }
  }
}

extern "C" void kernel_launch(void* const* d_in, const int* in_sizes, int n_in,
                              void* d_out, int out_size, void* d_ws, size_t ws_size,
                              hipStream_t stream) {
  const float* q = (const float*)d_in[0];
  const float* k = (const float*)d_in[1];
  const float* v = (const float*)d_in[2];
  const float* p = (const float*)d_in[3];
  float* out = (float*)d_out;
  unsigned short* Kt = (unsigned short*)d_ws;
  unsigned short* Vt = (unsigned short*)((char*)d_ws + (size_t)4 * 1024 * 1024);
  unsigned* sm = (unsigned*)((char*)d_ws + (size_t)8 * 1024 * 1024);

  prep_kernel<<<4608, 256, 0, stream>>>(k, v, p, Kt, Vt, sm);
  attn_kernel<<<512, 256, 0, stream>>>(Kt, Vt, q, sm, out);
}